// Round 13
// baseline (541.030 us; speedup 1.0000x reference)
//
#include <hip/hip_runtime.h>
#include <hip/hip_bf16.h>
#include <math.h>

// N = 65536 nodes, E = 524288 edges, HID = 128, 128 graphs x 512 nodes
// fp32 throughout: absmax threshold ~9.8e-8 forbids bf16 MFMA.
// ROUND 13: r12 proved launch_bounds can't force gather depth (VGPR stayed
// 64 -- it's a cap, not a target; compiler batches gathers regardless).
// The lever that DID work (r9: 66->62) was waves/CU (8->16). Reference:
// standalone aggregate with the same 16-gather structure sustains 3.8 TB/s
// at up to 32 waves/CU vs agg_gemm's 2.27 at 16. So: push that axis to its
// end -- 1024 thr/block, grid 512 = 2 blocks/CU x 16 waves = 32 waves/CU
// (100% occupancy). Needs VGPR<=64 (launch_bounds(1024,8)); safe: acc
// shrinks to [4][4]=16 regs (compiler fit VGPR=64 with acc=32 at 512 thr,
// no spill), ~58 regs needed. agg: 1 node/thread/panel. gemm: 32x32 thread
// grid, float4 A/B reads. W panel: exactly 1 float4/thread. LDS unchanged.
// All other kernels byte-identical to r9/r12.

#define SLOTS 48

static __device__ __forceinline__ float4 f4add(float4 a, float4 b) {
    return make_float4(a.x + b.x, a.y + b.y, a.z + b.z, a.w + b.w);
}
static __device__ __forceinline__ float4 f4fma(float s, float4 a, float4 acc) {
    return make_float4(fmaf(s, a.x, acc.x), fmaf(s, a.y, acc.y),
                       fmaf(s, a.z, acc.z), fmaf(s, a.w, acc.w));
}

// ============ Fused: edge count+scatter (blocks 0..EB-1)  +  weight fold ====
__global__ __launch_bounds__(256) void build_graph_fold(
    const int* __restrict__ src, const int* __restrict__ dst,
    int* __restrict__ cnt, int* __restrict__ csr_pad, int E, int EB,
    const float* __restrict__ embW, const float* __restrict__ embb,
    const float* __restrict__ W0, float* __restrict__ W01,
    float* __restrict__ b01, float* __restrict__ zrowA,
    float* __restrict__ zrowB)
{
    const int b = blockIdx.x;
    if (b < EB) {
        int e = b * 256 + threadIdx.x;
        if (e < E) {
            int d = dst[e];
            int r = atomicAdd(&cnt[d], 1);
            if (r < SLOTS) csr_pad[d * SLOTS + r] = src[e];
        }
        return;
    }
    // ---- weight fold ----
    __shared__ float rs[128];
    __shared__ float part[256];
    const int r = b - EB;           // 0..128; r==128 -> bias row
    const int t = threadIdx.x;
    if (r == 0 && t < 128) { zrowA[t] = 0.f; zrowB[t] = 0.f; }
    const int c = t & 127, q = t >> 7;  // q in {0,1}
    if (t < 128) rs[t] = (r < 128) ? embW[r * 128 + t] : embb[t];
    __syncthreads();
    float s = 0.f;
    const int k0 = q * 64;
#pragma unroll 8
    for (int k = k0; k < k0 + 64; k++) s = fmaf(rs[k], W0[k * 128 + c], s);
    part[t] = s;
    __syncthreads();
    if (q == 0) {
        float v = part[c] + part[c + 128];
        if (r < 128) W01[r * 128 + c] = v;
        else         b01[c] = v;
    }
}

// ============================ GEMM: [n,128] @ [128,128] =====================
// Proven structure (44us): BM=128, 256 thr, 8x8 microtile, single-buffered
// LDS, register prefetch. ASTRIDE=129 (==1 mod 32). WSTRIDE=140 + col
// swizzle c->c+4*(c>>5). Epilogue: out = (acc + bias) * rsqrt(deg[row]+1).
#define ASTRIDE 129
#define WSTRIDE 140
__global__ __launch_bounds__(256) void gemm128(
    const float* __restrict__ A, const float* __restrict__ W,
    const float* __restrict__ bias, const int* __restrict__ rowdeg,
    float* __restrict__ out, int n)
{
    __shared__ float As[32 * ASTRIDE];  // [k][m] transposed
    __shared__ float Ws[32 * WSTRIDE];  // [k][c'] swizzled
    const int tid  = threadIdx.x;
    const int rb   = blockIdx.x * 128;
    const int tc   = tid & 15;
    const int tr   = tid >> 4;
    const int colg = tc * 8;
    const int cswz = colg + ((colg >> 5) << 2);
    const int rowg = tr * 8;

    const int a_kq = tid & 7;
    const int a_m  = tid >> 3;
    const int w_c  = (tid & 31) * 4;
    const int w_cs = w_c + ((w_c >> 5) << 2);
    const int w_k  = tid >> 5;

    float acc[8][8];
#pragma unroll
    for (int i = 0; i < 8; i++)
#pragma unroll
        for (int j = 0; j < 8; j++) acc[i][j] = 0.f;

    float4 areg[4], wreg[4];
#pragma unroll
    for (int t = 0; t < 4; t++)
        areg[t] = *(const float4*)&A[(size_t)(rb + t * 32 + a_m) * 128 + a_kq * 4];
#pragma unroll
    for (int t = 0; t < 4; t++)
        wreg[t] = *(const float4*)&W[(size_t)(t * 8 + w_k) * 128 + w_c];

#pragma unroll 1
    for (int k0 = 0; k0 < 128; k0 += 32) {
#pragma unroll
        for (int t = 0; t < 4; t++) {
            const int m = t * 32 + a_m;
            const float4 av = areg[t];
            As[(a_kq * 4 + 0) * ASTRIDE + m] = av.x;
            As[(a_kq * 4 + 1) * ASTRIDE + m] = av.y;
            As[(a_kq * 4 + 2) * ASTRIDE + m] = av.z;
            As[(a_kq * 4 + 3) * ASTRIDE + m] = av.w;
        }
#pragma unroll
        for (int t = 0; t < 4; t++)
            *(float4*)&Ws[(t * 8 + w_k) * WSTRIDE + w_cs] = wreg[t];
        __syncthreads();
        if (k0 < 96) {
#pragma unroll
            for (int t = 0; t < 4; t++)
                areg[t] = *(const float4*)&A[(size_t)(rb + t * 32 + a_m) * 128 + k0 + 32 + a_kq * 4];
#pragma unroll
            for (int t = 0; t < 4; t++)
                wreg[t] = *(const float4*)&W[(size_t)(k0 + 32 + t * 8 + w_k) * 128 + w_c];
        }
#pragma unroll 8
        for (int kk = 0; kk < 32; kk++) {
            float4 a0 = *(const float4*)&As[kk * ASTRIDE + rowg];
            float4 a1 = *(const float4*)&As[kk * ASTRIDE + rowg + 4];
            float4 b0 = *(const float4*)&Ws[kk * WSTRIDE + cswz];
            float4 b1 = *(const float4*)&Ws[kk * WSTRIDE + cswz + 4];
            float av[8] = {a0.x, a0.y, a0.z, a0.w, a1.x, a1.y, a1.z, a1.w};
            float bv[8] = {b0.x, b0.y, b0.z, b0.w, b1.x, b1.y, b1.z, b1.w};
#pragma unroll
            for (int i = 0; i < 8; i++)
#pragma unroll
                for (int j = 0; j < 8; j++) acc[i][j] = fmaf(av[i], bv[j], acc[i][j]);
        }
        __syncthreads();
    }

    float4 bb0 = make_float4(0.f, 0.f, 0.f, 0.f), bb1 = bb0;
    if (bias) {
        bb0 = *(const float4*)&bias[colg];
        bb1 = *(const float4*)&bias[colg + 4];
    }
#pragma unroll
    for (int i = 0; i < 8; i++) {
        const int row  = rb + rowg + i;
        const float sc = rowdeg ? rsqrtf((float)(rowdeg[row] + 1)) : 1.f;
        float4 o0, o1;
        o0.x = (acc[i][0] + bb0.x) * sc;  o0.y = (acc[i][1] + bb0.y) * sc;
        o0.z = (acc[i][2] + bb0.z) * sc;  o0.w = (acc[i][3] + bb0.w) * sc;
        o1.x = (acc[i][4] + bb1.x) * sc;  o1.y = (acc[i][5] + bb1.y) * sc;
        o1.z = (acc[i][6] + bb1.z) * sc;  o1.w = (acc[i][7] + bb1.w) * sc;
        *(float4*)&out[(size_t)row * 128 + colg]     = o0;
        *(float4*)&out[(size_t)row * 128 + colg + 4] = o1;
    }
}

// ======== FUSED aggregate_l + gemm_{l+1}, BM=128, 1024 threads ==============
// Lock-step 2-barrier panel structure (proven). 1024 thr x grid 512 =
// 2 blocks/CU x 16 waves = 32 waves/CU (100% occupancy) for the gather
// phase -- the standalone aggregate's regime (3.8 TB/s). VGPR<=64 forced
// by launch_bounds(1024,8); acc[4][4]=16 regs so no spill expected.
// agg: 1 node/thread/panel (nd 0..127, ln 0..7). gemm: 32x32 thread grid,
// acc[4][4], one float4 A + one float4 B read per kk.
__global__ __launch_bounds__(1024, 8) void agg_gemm(
    const float* __restrict__ hs_in, const int* __restrict__ csr_pad,
    const int* __restrict__ cnt, const float* __restrict__ aggb,
    const float* __restrict__ W, float* __restrict__ hs_out, int n)
{
    __shared__ int   s_idx[128 * 17];   // clamped CSR, stride 17 (bank-free)
    __shared__ float s_dinv[128];
    __shared__ int   s_deg[128];
    __shared__ float As[32 * ASTRIDE];
    __shared__ float Ws[32 * WSTRIDE];

    const int tid = threadIdx.x;
    const int rb  = blockIdx.x * 128;
    const float4* __restrict__ hv = (const float4*)hs_in;

    if (tid < 128) {
        int d = cnt[rb + tid];
        s_deg[tid]  = d;
        s_dinv[tid] = rsqrtf((float)(d + 1));
    }
    if (tid < 512) {  // load + clamp CSR: thread t -> node t>>2, quad t&3
        const int m    = tid >> 2;
        const int q4   = (tid & 3) * 4;
        const int node = rb + m;
        const int4 c4 = *(const int4*)&csr_pad[node * SLOTS + q4];
        const int  d  = cnt[node];
        int* row = &s_idx[m * 17 + q4];
        row[0] = (q4 + 0 < d) ? c4.x : n;
        row[1] = (q4 + 1 < d) ? c4.y : n;
        row[2] = (q4 + 2 < d) ? c4.z : n;
        row[3] = (q4 + 3 < d) ? c4.w : n;
    }
    __syncthreads();

    // gemm thread mapping: 128x128 tile, acc[4][4], 1024 threads (32x32)
    const int tc   = tid & 31;          // 32 col groups of 4
    const int tr   = tid >> 5;          // 0..31 row groups of 4
    const int colg = tc * 4;
    const int cswz = colg + ((colg >> 5) << 2);
    const int rowg = tr * 4;
    const int w_c  = (tid & 31) * 4;
    const int w_cs = w_c + ((w_c >> 5) << 2);
    const int w_k  = tid >> 5;          // 0..31: one k-row per thread
    // agg thread mapping: 8 lanes/node (float4 each), 128 nodes (all)
    const int ln = tid & 7;
    const int nd = tid >> 3;            // 0..127

    float acc[4][4];
#pragma unroll
    for (int i = 0; i < 4; i++)
#pragma unroll
        for (int j = 0; j < 4; j++) acc[i][j] = 0.f;

#pragma unroll 1
    for (int p = 0; p < 4; p++) {
        // issue W-panel load early (lands under the agg gathers)
        float4 wreg = *(const float4*)&W[(size_t)(p * 32 + w_k) * 128 + w_c];

        // ---- aggregate this 32-feature panel: 1 node per thread ----
        const int fo = p * 8 + ln;          // float4 offset within a row
        const float4 bb = *(const float4*)&aggb[p * 32 + ln * 4];
        {
            const int m    = nd;
            const int node = rb + m;
            const int* rowI = &s_idx[m * 17];
            float4 self = hv[(size_t)node * 32 + fo];
            float4 r[16];
#pragma unroll
            for (int j = 0; j < 16; j++)
                r[j] = hv[(size_t)rowI[j] * 32 + fo];
            asm volatile("" ::: "memory");
            float4 a0 = self;
            float4 a1 = make_float4(0.f, 0.f, 0.f, 0.f);
            float4 a2 = a1, a3 = a1;
#pragma unroll
            for (int j = 0; j < 16; j += 4) {
                a0 = f4add(a0, r[j + 0]);
                a1 = f4add(a1, r[j + 1]);
                a2 = f4add(a2, r[j + 2]);
                a3 = f4add(a3, r[j + 3]);
            }
            const int d    = s_deg[m];
            const int dcap = d < SLOTS ? d : SLOTS;
            for (int j = 16; j < dcap; j++)  // rare tail (deg > 16)
                a1 = f4add(a1, hv[(size_t)csr_pad[node * SLOTS + j] * 32 + fo]);
            float4 s = f4add(f4add(a0, a1), f4add(a2, a3));
            const float dv = s_dinv[m];
            float4 o;
            o.x = fmaxf(fmaf(s.x, dv, bb.x), 0.f);
            o.y = fmaxf(fmaf(s.y, dv, bb.y), 0.f);
            o.z = fmaxf(fmaf(s.z, dv, bb.z), 0.f);
            o.w = fmaxf(fmaf(s.w, dv, bb.w), 0.f);
            const int kb = ln * 4;
            As[(kb + 0) * ASTRIDE + m] = o.x;
            As[(kb + 1) * ASTRIDE + m] = o.y;
            As[(kb + 2) * ASTRIDE + m] = o.z;
            As[(kb + 3) * ASTRIDE + m] = o.w;
        }
        Ws[w_k * WSTRIDE + w_cs + 0] = wreg.x;
        Ws[w_k * WSTRIDE + w_cs + 1] = wreg.y;
        Ws[w_k * WSTRIDE + w_cs + 2] = wreg.z;
        Ws[w_k * WSTRIDE + w_cs + 3] = wreg.w;
        __syncthreads();

        // ---- gemm partial-K: acc[4][4], 1 float4 A + 1 float4 B per kk ----
#pragma unroll 8
        for (int kk = 0; kk < 32; kk++) {
            float4 a0 = *(const float4*)&As[kk * ASTRIDE + rowg];
            float4 b0 = *(const float4*)&Ws[kk * WSTRIDE + cswz];
            float av[4] = {a0.x, a0.y, a0.z, a0.w};
            float bv[4] = {b0.x, b0.y, b0.z, b0.w};
#pragma unroll
            for (int i = 0; i < 4; i++)
#pragma unroll
                for (int j = 0; j < 4; j++) acc[i][j] = fmaf(av[i], bv[j], acc[i][j]);
        }
        __syncthreads();
    }

    // epilogue: source-side dinv scaling for the next layer, no bias
#pragma unroll
    for (int i = 0; i < 4; i++) {
        const int row  = rb + rowg + i;
        const float sc = s_dinv[rowg + i];
        float4 o0;
        o0.x = acc[i][0] * sc;  o0.y = acc[i][1] * sc;
        o0.z = acc[i][2] * sc;  o0.w = acc[i][3] * sc;
        *(float4*)&hs_out[(size_t)row * 128 + colg] = o0;
    }
}

// ============================ Aggregation (last layer) ======================
// Proven r4 kernel, byte-identical: zero-row gather, int4 CSR loads,
// fused pooling score.
__global__ __launch_bounds__(256) void aggregate(
    const float* __restrict__ hs, const int* __restrict__ csr_pad,
    const int* __restrict__ cnt, const float* __restrict__ bias,
    float* __restrict__ hout,
    const float* __restrict__ pool_p, float* __restrict__ scores, int n)
{
    const int grp  = threadIdx.x >> 5;
    const int lane = threadIdx.x & 31;
    const int node = blockIdx.x * 8 + grp;
    const float4* __restrict__ hv = (const float4*)hs;

    const int deg = cnt[node];
    const int e0  = node * SLOTS;

    int4 c4[4];
#pragma unroll
    for (int q = 0; q < 4; q++)
        c4[q] = *(const int4*)&csr_pad[e0 + q * 4];
    int ix[16] = {c4[0].x, c4[0].y, c4[0].z, c4[0].w,
                  c4[1].x, c4[1].y, c4[1].z, c4[1].w,
                  c4[2].x, c4[2].y, c4[2].z, c4[2].w,
                  c4[3].x, c4[3].y, c4[3].z, c4[3].w};
#pragma unroll
    for (int j = 0; j < 16; j++)
        ix[j] = (j < deg) ? ix[j] : n;       // poison -> zero row

    float4 self = hv[(size_t)node * 32 + lane];
    float4 r[16];
#pragma unroll
    for (int j = 0; j < 16; j++)
        r[j] = hv[(size_t)ix[j] * 32 + lane];
    asm volatile("" ::: "memory");  // keep the 16 loads in flight before use

    float4 a0 = self;
    float4 a1 = make_float4(0.f, 0.f, 0.f, 0.f);
    float4 a2 = a1, a3 = a1;
#pragma unroll
    for (int j = 0; j < 16; j += 4) {
        a0 = f4add(a0, r[j + 0]);
        a1 = f4add(a1, r[j + 1]);
        a2 = f4add(a2, r[j + 2]);
        a3 = f4add(a3, r[j + 3]);
    }
    const int dcap = deg < SLOTS ? deg : SLOTS;
    for (int j = 16; j < dcap; j++) {  // rare tail (deg > 16)
        a1 = f4add(a1, hv[(size_t)csr_pad[e0 + j] * 32 + lane]);
    }

    float4 s = f4add(f4add(a0, a1), f4add(a2, a3));
    const float dv = rsqrtf((float)(deg + 1));
    const float4 bb = ((const float4*)bias)[lane];
    float4 o;
    o.x = fmaxf(fmaf(s.x, dv, bb.x), 0.f);
    o.y = fmaxf(fmaf(s.y, dv, bb.y), 0.f);
    o.z = fmaxf(fmaf(s.z, dv, bb.z), 0.f);
    o.w = fmaxf(fmaf(s.w, dv, bb.w), 0.f);
    ((float4*)hout)[(size_t)node * 32 + lane] = o;

    if (scores) {  // wave-uniform branch (fused pooling score)
        float4 pv = ((const float4*)pool_p)[lane];
        float d  = o.x * pv.x + o.y * pv.y + o.z * pv.z + o.w * pv.w;
        float nn = pv.x * pv.x + pv.y * pv.y + pv.z * pv.z + pv.w * pv.w;
#pragma unroll
        for (int off = 16; off > 0; off >>= 1) {
            d  += __shfl_xor(d, off);
            nn += __shfl_xor(nn, off);
        }
        if (lane == 0) scores[node] = d * rsqrtf(nn);
    }
}

// ==================== TopK pool (k=256 of 512) + MLP head ===================
__global__ __launch_bounds__(512) void topk_mlp(
    const float* __restrict__ scores, const float* __restrict__ h,
    const float* __restrict__ fc1W, const float* __restrict__ fc1b,
    const float* __restrict__ fc2W, const float* __restrict__ fc2b,
    const float* __restrict__ fc3W, const float* __restrict__ fc3b,
    float* __restrict__ out)
{
    __shared__ float s[512];
    __shared__ int   sel[256];
    __shared__ float w[256];
    __shared__ float4 red[512];
    __shared__ float pld[128];
    __shared__ float z1[128];
    __shared__ float z2[64];
    const int g = blockIdx.x;
    const int i = threadIdx.x;
    s[i] = scores[g * 512 + i];
    __syncthreads();
    float si = s[i];
    int rank = 0;
    for (int j = 0; j < 512; j++) {
        float sj = s[j];
        rank += (sj > si) || (sj == si && j < i);
    }
    if (rank < 256) {
        sel[rank] = i;
        w[rank]   = tanhf(si) * (1.f / 256.f);
    }
    __syncthreads();
    const int c   = (i & 31) * 4;
    const int grp = i >> 5;
    float4 acc = make_float4(0.f, 0.f, 0.f, 0.f);
    for (int t = grp; t < 256; t += 16) {
        float wt  = w[t];
        int   idx = sel[t];
        float4 r = *(const float4*)&h[((size_t)g * 512 + idx) * 128 + c];
        acc = f4fma(wt, r, acc);
    }
    red[i] = acc;
    __syncthreads();
    if (i < 256) red[i] = f4add(red[i], red[i + 256]);
    __syncthreads();
    if (i < 128) red[i] = f4add(red[i], red[i + 128]);
    __syncthreads();
    if (i < 64) red[i] = f4add(red[i], red[i + 64]);
    __syncthreads();
    if (i < 32) {
        float4 v = f4add(red[i], red[i + 32]);
        *(float4*)&pld[i * 4] = v;
    }
    __syncthreads();
    if (i < 128) {
        float a = fc1b[i];
        for (int k = 0; k < 128; k++) a += pld[k] * fc1W[k * 128 + i];
        z1[i] = fmaxf(a, 0.f);
    }
    __syncthreads();
    if (i < 64) {
        float b = fc2b[i];
        for (int k = 0; k < 128; k++) b += z1[k] * fc2W[k * 64 + i];
        z2[i] = fmaxf(b, 0.f);
    }
    __syncthreads();
    if (i < 10) {
        float o = fc3b[i];
        for (int k = 0; k < 64; k++) o += z2[k] * fc3W[k * 10 + i];
        out[g * 10 + i] = o;
    }
}

// ============================ Launcher ======================================
extern "C" void kernel_launch(void* const* d_in, const int* in_sizes, int n_in,
                              void* d_out, int out_size, void* d_ws, size_t ws_size,
                              hipStream_t stream)
{
    const float* x     = (const float*)d_in[0];
    const int*   eidx  = (const int*)d_in[1];
    const float* embW  = (const float*)d_in[3];
    const float* embb  = (const float*)d_in[4];
    const float* gcnW  = (const float*)d_in[5];
    const float* gcnb  = (const float*)d_in[6];
    const float* poolp = (const float*)d_in[7];
    const float* fc1W  = (const float*)d_in[8];
    const float* fc1b  = (const float*)d_in[9];
    const float* fc2W  = (const float*)d_in[10];
    const float* fc2b  = (const float*)d_in[11];
    const float* fc3W  = (const float*)d_in[12];
    const float* fc3b  = (const float*)d_in[13];
    float* out = (float*)d_out;

    const int n = in_sizes[0] / 128;   // 65536
    const int E = in_sizes[1] / 2;     // 524288
    const int G = n / 512;             // 128

    const int* src = eidx;
    const int* dst = eidx + E;

    char* ws = (char*)d_ws;
    size_t off = 0;
    auto carve = [&](size_t bytes) {
        void* p = ws + off;
        off += (bytes + 255) & ~(size_t)255;
        return p;
    };
    float* h       = (float*)carve((size_t)n * 128 * 4);
    float* hsA     = (float*)carve((size_t)(n + 1) * 128 * 4);  // +zero row
    float* hsB     = (float*)carve((size_t)(n + 1) * 128 * 4);  // +zero row
    int*   cnt     = (int*)carve((size_t)n * 4);
    int*   csr_pad = (int*)carve((size_t)n * SLOTS * 4);
    float* scores  = (float*)carve((size_t)n * 4);
    float* W01     = (float*)carve(128 * 128 * 4);
    float* b01     = (float*)carve(128 * 4);
    (void)ws_size;

    const int EB = E / 256;            // 2048 edge blocks

    // ---- zero degree counters, then fused CSR build + weight fold ----
    hipMemsetAsync(cnt, 0, (size_t)n * 4, stream);
    build_graph_fold<<<EB + 129, 256, 0, stream>>>(
        src, dst, cnt, csr_pad, E, EB, embW, embb, gcnW, W01, b01,
        hsA + (size_t)n * 128, hsB + (size_t)n * 128);

    // ---- layer 0 GEMM (folded embedding) -> hsA ----
    gemm128<<<n / 128, 256, 0, stream>>>(x, W01, b01, cnt, hsA, n);

    // ---- fused agg0+gemm1 (hsA->hsB), agg1+gemm2 (hsB->hsA) ----
    agg_gemm<<<n / 128, 1024, 0, stream>>>(hsA, csr_pad, cnt, gcnb,
                                           gcnW + (size_t)1 * 128 * 128, hsB, n);
    agg_gemm<<<n / 128, 1024, 0, stream>>>(hsB, csr_pad, cnt, gcnb + 128,
                                           gcnW + (size_t)2 * 128 * 128, hsA, n);

    // ---- last aggregate (h + fused pooling scores) ----
    aggregate<<<n / 8, 256, 0, stream>>>(hsA, csr_pad, cnt, gcnb + 256, h,
                                         poolp, scores, n);

    // ---- fused topk pool + MLP ----
    topk_mlp<<<G, 512, 0, stream>>>(scores, h, fc1W, fc1b, fc2W, fc2b,
                                    fc3W, fc3b, out);
}

// Round 14
// 385.200 us; speedup vs baseline: 1.4045x; 1.4045x over previous
//
#include <hip/hip_runtime.h>
#include <hip/hip_bf16.h>
#include <math.h>

// N = 65536 nodes, E = 524288 edges, HID = 128, 128 graphs x 512 nodes
// fp32 throughout: absmax threshold ~9.8e-8 forbids bf16 MFMA.
// ROUND 14: r13's 1024-thr config CONFIRMED the mechanism (76% occupancy
// -> 4.18 TB/s, highest of the session) but (1024,8) forced VGPR=32 and
// r[16] spilled (WRITE 33->319MB, 160us). Fix: same 1024-thr geometry
// (mappings verified correct in r13), gather split into TWO SEQUENTIAL
// batches of 8 (peak live ~56 regs < 64) and PLAIN launch_bounds(1024)
// (no min-waves forcing -- that's what produced the 32-reg alloc).
// Natural alloc <=64 -> 2 blocks/CU x 16 waves = 32 waves/CU, no spill.
// Per-CU outstanding gathers: 32 waves x 8 = 256 vs r9's ~80.
// All other kernels byte-identical to r9/r12.

#define SLOTS 48

static __device__ __forceinline__ float4 f4add(float4 a, float4 b) {
    return make_float4(a.x + b.x, a.y + b.y, a.z + b.z, a.w + b.w);
}
static __device__ __forceinline__ float4 f4fma(float s, float4 a, float4 acc) {
    return make_float4(fmaf(s, a.x, acc.x), fmaf(s, a.y, acc.y),
                       fmaf(s, a.z, acc.z), fmaf(s, a.w, acc.w));
}

// ============ Fused: edge count+scatter (blocks 0..EB-1)  +  weight fold ====
__global__ __launch_bounds__(256) void build_graph_fold(
    const int* __restrict__ src, const int* __restrict__ dst,
    int* __restrict__ cnt, int* __restrict__ csr_pad, int E, int EB,
    const float* __restrict__ embW, const float* __restrict__ embb,
    const float* __restrict__ W0, float* __restrict__ W01,
    float* __restrict__ b01, float* __restrict__ zrowA,
    float* __restrict__ zrowB)
{
    const int b = blockIdx.x;
    if (b < EB) {
        int e = b * 256 + threadIdx.x;
        if (e < E) {
            int d = dst[e];
            int r = atomicAdd(&cnt[d], 1);
            if (r < SLOTS) csr_pad[d * SLOTS + r] = src[e];
        }
        return;
    }
    // ---- weight fold ----
    __shared__ float rs[128];
    __shared__ float part[256];
    const int r = b - EB;           // 0..128; r==128 -> bias row
    const int t = threadIdx.x;
    if (r == 0 && t < 128) { zrowA[t] = 0.f; zrowB[t] = 0.f; }
    const int c = t & 127, q = t >> 7;  // q in {0,1}
    if (t < 128) rs[t] = (r < 128) ? embW[r * 128 + t] : embb[t];
    __syncthreads();
    float s = 0.f;
    const int k0 = q * 64;
#pragma unroll 8
    for (int k = k0; k < k0 + 64; k++) s = fmaf(rs[k], W0[k * 128 + c], s);
    part[t] = s;
    __syncthreads();
    if (q == 0) {
        float v = part[c] + part[c + 128];
        if (r < 128) W01[r * 128 + c] = v;
        else         b01[c] = v;
    }
}

// ============================ GEMM: [n,128] @ [128,128] =====================
// Proven structure (44us): BM=128, 256 thr, 8x8 microtile, single-buffered
// LDS, register prefetch. ASTRIDE=129 (==1 mod 32). WSTRIDE=140 + col
// swizzle c->c+4*(c>>5). Epilogue: out = (acc + bias) * rsqrt(deg[row]+1).
#define ASTRIDE 129
#define WSTRIDE 140
__global__ __launch_bounds__(256) void gemm128(
    const float* __restrict__ A, const float* __restrict__ W,
    const float* __restrict__ bias, const int* __restrict__ rowdeg,
    float* __restrict__ out, int n)
{
    __shared__ float As[32 * ASTRIDE];  // [k][m] transposed
    __shared__ float Ws[32 * WSTRIDE];  // [k][c'] swizzled
    const int tid  = threadIdx.x;
    const int rb   = blockIdx.x * 128;
    const int tc   = tid & 15;
    const int tr   = tid >> 4;
    const int colg = tc * 8;
    const int cswz = colg + ((colg >> 5) << 2);
    const int rowg = tr * 8;

    const int a_kq = tid & 7;
    const int a_m  = tid >> 3;
    const int w_c  = (tid & 31) * 4;
    const int w_cs = w_c + ((w_c >> 5) << 2);
    const int w_k  = tid >> 5;

    float acc[8][8];
#pragma unroll
    for (int i = 0; i < 8; i++)
#pragma unroll
        for (int j = 0; j < 8; j++) acc[i][j] = 0.f;

    float4 areg[4], wreg[4];
#pragma unroll
    for (int t = 0; t < 4; t++)
        areg[t] = *(const float4*)&A[(size_t)(rb + t * 32 + a_m) * 128 + a_kq * 4];
#pragma unroll
    for (int t = 0; t < 4; t++)
        wreg[t] = *(const float4*)&W[(size_t)(t * 8 + w_k) * 128 + w_c];

#pragma unroll 1
    for (int k0 = 0; k0 < 128; k0 += 32) {
#pragma unroll
        for (int t = 0; t < 4; t++) {
            const int m = t * 32 + a_m;
            const float4 av = areg[t];
            As[(a_kq * 4 + 0) * ASTRIDE + m] = av.x;
            As[(a_kq * 4 + 1) * ASTRIDE + m] = av.y;
            As[(a_kq * 4 + 2) * ASTRIDE + m] = av.z;
            As[(a_kq * 4 + 3) * ASTRIDE + m] = av.w;
        }
#pragma unroll
        for (int t = 0; t < 4; t++)
            *(float4*)&Ws[(t * 8 + w_k) * WSTRIDE + w_cs] = wreg[t];
        __syncthreads();
        if (k0 < 96) {
#pragma unroll
            for (int t = 0; t < 4; t++)
                areg[t] = *(const float4*)&A[(size_t)(rb + t * 32 + a_m) * 128 + k0 + 32 + a_kq * 4];
#pragma unroll
            for (int t = 0; t < 4; t++)
                wreg[t] = *(const float4*)&W[(size_t)(k0 + 32 + t * 8 + w_k) * 128 + w_c];
        }
#pragma unroll 8
        for (int kk = 0; kk < 32; kk++) {
            float4 a0 = *(const float4*)&As[kk * ASTRIDE + rowg];
            float4 a1 = *(const float4*)&As[kk * ASTRIDE + rowg + 4];
            float4 b0 = *(const float4*)&Ws[kk * WSTRIDE + cswz];
            float4 b1 = *(const float4*)&Ws[kk * WSTRIDE + cswz + 4];
            float av[8] = {a0.x, a0.y, a0.z, a0.w, a1.x, a1.y, a1.z, a1.w};
            float bv[8] = {b0.x, b0.y, b0.z, b0.w, b1.x, b1.y, b1.z, b1.w};
#pragma unroll
            for (int i = 0; i < 8; i++)
#pragma unroll
                for (int j = 0; j < 8; j++) acc[i][j] = fmaf(av[i], bv[j], acc[i][j]);
        }
        __syncthreads();
    }

    float4 bb0 = make_float4(0.f, 0.f, 0.f, 0.f), bb1 = bb0;
    if (bias) {
        bb0 = *(const float4*)&bias[colg];
        bb1 = *(const float4*)&bias[colg + 4];
    }
#pragma unroll
    for (int i = 0; i < 8; i++) {
        const int row  = rb + rowg + i;
        const float sc = rowdeg ? rsqrtf((float)(rowdeg[row] + 1)) : 1.f;
        float4 o0, o1;
        o0.x = (acc[i][0] + bb0.x) * sc;  o0.y = (acc[i][1] + bb0.y) * sc;
        o0.z = (acc[i][2] + bb0.z) * sc;  o0.w = (acc[i][3] + bb0.w) * sc;
        o1.x = (acc[i][4] + bb1.x) * sc;  o1.y = (acc[i][5] + bb1.y) * sc;
        o1.z = (acc[i][6] + bb1.z) * sc;  o1.w = (acc[i][7] + bb1.w) * sc;
        *(float4*)&out[(size_t)row * 128 + colg]     = o0;
        *(float4*)&out[(size_t)row * 128 + colg + 4] = o1;
    }
}

// ======== FUSED aggregate_l + gemm_{l+1}, BM=128, 1024 threads ==============
// r13 mappings (verified correct), gather restructured: two sequential
// batches of 8 (peak live ~56 regs) and NO min-waves bound. Natural
// VGPR <= 64 -> 2 blocks/CU x 16 waves = 32 waves/CU, zero spill.
__global__ __launch_bounds__(1024) void agg_gemm(
    const float* __restrict__ hs_in, const int* __restrict__ csr_pad,
    const int* __restrict__ cnt, const float* __restrict__ aggb,
    const float* __restrict__ W, float* __restrict__ hs_out, int n)
{
    __shared__ int   s_idx[128 * 17];   // clamped CSR, stride 17 (bank-free)
    __shared__ float s_dinv[128];
    __shared__ int   s_deg[128];
    __shared__ float As[32 * ASTRIDE];
    __shared__ float Ws[32 * WSTRIDE];

    const int tid = threadIdx.x;
    const int rb  = blockIdx.x * 128;
    const float4* __restrict__ hv = (const float4*)hs_in;

    if (tid < 128) {
        int d = cnt[rb + tid];
        s_deg[tid]  = d;
        s_dinv[tid] = rsqrtf((float)(d + 1));
    }
    if (tid < 512) {  // load + clamp CSR: thread t -> node t>>2, quad t&3
        const int m    = tid >> 2;
        const int q4   = (tid & 3) * 4;
        const int node = rb + m;
        const int4 c4 = *(const int4*)&csr_pad[node * SLOTS + q4];
        const int  d  = cnt[node];
        int* row = &s_idx[m * 17 + q4];
        row[0] = (q4 + 0 < d) ? c4.x : n;
        row[1] = (q4 + 1 < d) ? c4.y : n;
        row[2] = (q4 + 2 < d) ? c4.z : n;
        row[3] = (q4 + 3 < d) ? c4.w : n;
    }
    __syncthreads();

    // gemm thread mapping: 128x128 tile, acc[4][4], 1024 threads (32x32)
    const int tc   = tid & 31;          // 32 col groups of 4
    const int tr   = tid >> 5;          // 0..31 row groups of 4
    const int colg = tc * 4;
    const int cswz = colg + ((colg >> 5) << 2);
    const int rowg = tr * 4;
    const int w_c  = (tid & 31) * 4;
    const int w_cs = w_c + ((w_c >> 5) << 2);
    const int w_k  = tid >> 5;          // 0..31: one k-row per thread
    // agg thread mapping: 8 lanes/node (float4 each), 128 nodes (all)
    const int ln = tid & 7;
    const int nd = tid >> 3;            // 0..127

    float acc[4][4];
#pragma unroll
    for (int i = 0; i < 4; i++)
#pragma unroll
        for (int j = 0; j < 4; j++) acc[i][j] = 0.f;

#pragma unroll 1
    for (int p = 0; p < 4; p++) {
        // issue W-panel load early (lands under the agg gathers)
        float4 wreg = *(const float4*)&W[(size_t)(p * 32 + w_k) * 128 + w_c];

        // ---- aggregate this 32-feature panel: 1 node per thread ----
        const int fo = p * 8 + ln;          // float4 offset within a row
        const float4 bb = *(const float4*)&aggb[p * 32 + ln * 4];
        {
            const int m    = nd;
            const int node = rb + m;
            const int* rowI = &s_idx[m * 17];
            float4 a0 = hv[(size_t)node * 32 + fo];   // self
            float4 a1 = make_float4(0.f, 0.f, 0.f, 0.f);
            float4 a2 = a1, a3 = a1;
            // two sequential batches of 8 gathers (peak live = 8 float4)
#pragma unroll 1
            for (int hb = 0; hb < 2; hb++) {
                float4 r[8];
#pragma unroll
                for (int j = 0; j < 8; j++)
                    r[j] = hv[(size_t)rowI[hb * 8 + j] * 32 + fo];
                asm volatile("" ::: "memory");
                a0 = f4add(a0, r[0]);  a1 = f4add(a1, r[1]);
                a2 = f4add(a2, r[2]);  a3 = f4add(a3, r[3]);
                a0 = f4add(a0, r[4]);  a1 = f4add(a1, r[5]);
                a2 = f4add(a2, r[6]);  a3 = f4add(a3, r[7]);
            }
            const int d    = s_deg[m];
            const int dcap = d < SLOTS ? d : SLOTS;
            for (int j = 16; j < dcap; j++)  // rare tail (deg > 16)
                a1 = f4add(a1, hv[(size_t)csr_pad[node * SLOTS + j] * 32 + fo]);
            float4 s = f4add(f4add(a0, a1), f4add(a2, a3));
            const float dv = s_dinv[m];
            float4 o;
            o.x = fmaxf(fmaf(s.x, dv, bb.x), 0.f);
            o.y = fmaxf(fmaf(s.y, dv, bb.y), 0.f);
            o.z = fmaxf(fmaf(s.z, dv, bb.z), 0.f);
            o.w = fmaxf(fmaf(s.w, dv, bb.w), 0.f);
            const int kb = ln * 4;
            As[(kb + 0) * ASTRIDE + m] = o.x;
            As[(kb + 1) * ASTRIDE + m] = o.y;
            As[(kb + 2) * ASTRIDE + m] = o.z;
            As[(kb + 3) * ASTRIDE + m] = o.w;
        }
        Ws[w_k * WSTRIDE + w_cs + 0] = wreg.x;
        Ws[w_k * WSTRIDE + w_cs + 1] = wreg.y;
        Ws[w_k * WSTRIDE + w_cs + 2] = wreg.z;
        Ws[w_k * WSTRIDE + w_cs + 3] = wreg.w;
        __syncthreads();

        // ---- gemm partial-K: acc[4][4], 1 float4 A + 1 float4 B per kk ----
#pragma unroll 8
        for (int kk = 0; kk < 32; kk++) {
            float4 a0 = *(const float4*)&As[kk * ASTRIDE + rowg];
            float4 b0 = *(const float4*)&Ws[kk * WSTRIDE + cswz];
            float av[4] = {a0.x, a0.y, a0.z, a0.w};
            float bv[4] = {b0.x, b0.y, b0.z, b0.w};
#pragma unroll
            for (int i = 0; i < 4; i++)
#pragma unroll
                for (int j = 0; j < 4; j++) acc[i][j] = fmaf(av[i], bv[j], acc[i][j]);
        }
        __syncthreads();
    }

    // epilogue: source-side dinv scaling for the next layer, no bias
#pragma unroll
    for (int i = 0; i < 4; i++) {
        const int row  = rb + rowg + i;
        const float sc = s_dinv[rowg + i];
        float4 o0;
        o0.x = acc[i][0] * sc;  o0.y = acc[i][1] * sc;
        o0.z = acc[i][2] * sc;  o0.w = acc[i][3] * sc;
        *(float4*)&hs_out[(size_t)row * 128 + colg] = o0;
    }
}

// ============================ Aggregation (last layer) ======================
// Proven r4 kernel, byte-identical: zero-row gather, int4 CSR loads,
// fused pooling score.
__global__ __launch_bounds__(256) void aggregate(
    const float* __restrict__ hs, const int* __restrict__ csr_pad,
    const int* __restrict__ cnt, const float* __restrict__ bias,
    float* __restrict__ hout,
    const float* __restrict__ pool_p, float* __restrict__ scores, int n)
{
    const int grp  = threadIdx.x >> 5;
    const int lane = threadIdx.x & 31;
    const int node = blockIdx.x * 8 + grp;
    const float4* __restrict__ hv = (const float4*)hs;

    const int deg = cnt[node];
    const int e0  = node * SLOTS;

    int4 c4[4];
#pragma unroll
    for (int q = 0; q < 4; q++)
        c4[q] = *(const int4*)&csr_pad[e0 + q * 4];
    int ix[16] = {c4[0].x, c4[0].y, c4[0].z, c4[0].w,
                  c4[1].x, c4[1].y, c4[1].z, c4[1].w,
                  c4[2].x, c4[2].y, c4[2].z, c4[2].w,
                  c4[3].x, c4[3].y, c4[3].z, c4[3].w};
#pragma unroll
    for (int j = 0; j < 16; j++)
        ix[j] = (j < deg) ? ix[j] : n;       // poison -> zero row

    float4 self = hv[(size_t)node * 32 + lane];
    float4 r[16];
#pragma unroll
    for (int j = 0; j < 16; j++)
        r[j] = hv[(size_t)ix[j] * 32 + lane];
    asm volatile("" ::: "memory");  // keep the 16 loads in flight before use

    float4 a0 = self;
    float4 a1 = make_float4(0.f, 0.f, 0.f, 0.f);
    float4 a2 = a1, a3 = a1;
#pragma unroll
    for (int j = 0; j < 16; j += 4) {
        a0 = f4add(a0, r[j + 0]);
        a1 = f4add(a1, r[j + 1]);
        a2 = f4add(a2, r[j + 2]);
        a3 = f4add(a3, r[j + 3]);
    }
    const int dcap = deg < SLOTS ? deg : SLOTS;
    for (int j = 16; j < dcap; j++) {  // rare tail (deg > 16)
        a1 = f4add(a1, hv[(size_t)csr_pad[e0 + j] * 32 + lane]);
    }

    float4 s = f4add(f4add(a0, a1), f4add(a2, a3));
    const float dv = rsqrtf((float)(deg + 1));
    const float4 bb = ((const float4*)bias)[lane];
    float4 o;
    o.x = fmaxf(fmaf(s.x, dv, bb.x), 0.f);
    o.y = fmaxf(fmaf(s.y, dv, bb.y), 0.f);
    o.z = fmaxf(fmaf(s.z, dv, bb.z), 0.f);
    o.w = fmaxf(fmaf(s.w, dv, bb.w), 0.f);
    ((float4*)hout)[(size_t)node * 32 + lane] = o;

    if (scores) {  // wave-uniform branch (fused pooling score)
        float4 pv = ((const float4*)pool_p)[lane];
        float d  = o.x * pv.x + o.y * pv.y + o.z * pv.z + o.w * pv.w;
        float nn = pv.x * pv.x + pv.y * pv.y + pv.z * pv.z + pv.w * pv.w;
#pragma unroll
        for (int off = 16; off > 0; off >>= 1) {
            d  += __shfl_xor(d, off);
            nn += __shfl_xor(nn, off);
        }
        if (lane == 0) scores[node] = d * rsqrtf(nn);
    }
}

// ==================== TopK pool (k=256 of 512) + MLP head ===================
__global__ __launch_bounds__(512) void topk_mlp(
    const float* __restrict__ scores, const float* __restrict__ h,
    const float* __restrict__ fc1W, const float* __restrict__ fc1b,
    const float* __restrict__ fc2W, const float* __restrict__ fc2b,
    const float* __restrict__ fc3W, const float* __restrict__ fc3b,
    float* __restrict__ out)
{
    __shared__ float s[512];
    __shared__ int   sel[256];
    __shared__ float w[256];
    __shared__ float4 red[512];
    __shared__ float pld[128];
    __shared__ float z1[128];
    __shared__ float z2[64];
    const int g = blockIdx.x;
    const int i = threadIdx.x;
    s[i] = scores[g * 512 + i];
    __syncthreads();
    float si = s[i];
    int rank = 0;
    for (int j = 0; j < 512; j++) {
        float sj = s[j];
        rank += (sj > si) || (sj == si && j < i);
    }
    if (rank < 256) {
        sel[rank] = i;
        w[rank]   = tanhf(si) * (1.f / 256.f);
    }
    __syncthreads();
    const int c   = (i & 31) * 4;
    const int grp = i >> 5;
    float4 acc = make_float4(0.f, 0.f, 0.f, 0.f);
    for (int t = grp; t < 256; t += 16) {
        float wt  = w[t];
        int   idx = sel[t];
        float4 r = *(const float4*)&h[((size_t)g * 512 + idx) * 128 + c];
        acc = f4fma(wt, r, acc);
    }
    red[i] = acc;
    __syncthreads();
    if (i < 256) red[i] = f4add(red[i], red[i + 256]);
    __syncthreads();
    if (i < 128) red[i] = f4add(red[i], red[i + 128]);
    __syncthreads();
    if (i < 64) red[i] = f4add(red[i], red[i + 64]);
    __syncthreads();
    if (i < 32) {
        float4 v = f4add(red[i], red[i + 32]);
        *(float4*)&pld[i * 4] = v;
    }
    __syncthreads();
    if (i < 128) {
        float a = fc1b[i];
        for (int k = 0; k < 128; k++) a += pld[k] * fc1W[k * 128 + i];
        z1[i] = fmaxf(a, 0.f);
    }
    __syncthreads();
    if (i < 64) {
        float b = fc2b[i];
        for (int k = 0; k < 128; k++) b += z1[k] * fc2W[k * 64 + i];
        z2[i] = fmaxf(b, 0.f);
    }
    __syncthreads();
    if (i < 10) {
        float o = fc3b[i];
        for (int k = 0; k < 64; k++) o += z2[k] * fc3W[k * 10 + i];
        out[g * 10 + i] = o;
    }
}

// ============================ Launcher ======================================
extern "C" void kernel_launch(void* const* d_in, const int* in_sizes, int n_in,
                              void* d_out, int out_size, void* d_ws, size_t ws_size,
                              hipStream_t stream)
{
    const float* x     = (const float*)d_in[0];
    const int*   eidx  = (const int*)d_in[1];
    const float* embW  = (const float*)d_in[3];
    const float* embb  = (const float*)d_in[4];
    const float* gcnW  = (const float*)d_in[5];
    const float* gcnb  = (const float*)d_in[6];
    const float* poolp = (const float*)d_in[7];
    const float* fc1W  = (const float*)d_in[8];
    const float* fc1b  = (const float*)d_in[9];
    const float* fc2W  = (const float*)d_in[10];
    const float* fc2b  = (const float*)d_in[11];
    const float* fc3W  = (const float*)d_in[12];
    const float* fc3b  = (const float*)d_in[13];
    float* out = (float*)d_out;

    const int n = in_sizes[0] / 128;   // 65536
    const int E = in_sizes[1] / 2;     // 524288
    const int G = n / 512;             // 128

    const int* src = eidx;
    const int* dst = eidx + E;

    char* ws = (char*)d_ws;
    size_t off = 0;
    auto carve = [&](size_t bytes) {
        void* p = ws + off;
        off += (bytes + 255) & ~(size_t)255;
        return p;
    };
    float* h       = (float*)carve((size_t)n * 128 * 4);
    float* hsA     = (float*)carve((size_t)(n + 1) * 128 * 4);  // +zero row
    float* hsB     = (float*)carve((size_t)(n + 1) * 128 * 4);  // +zero row
    int*   cnt     = (int*)carve((size_t)n * 4);
    int*   csr_pad = (int*)carve((size_t)n * SLOTS * 4);
    float* scores  = (float*)carve((size_t)n * 4);
    float* W01     = (float*)carve(128 * 128 * 4);
    float* b01     = (float*)carve(128 * 4);
    (void)ws_size;

    const int EB = E / 256;            // 2048 edge blocks

    // ---- zero degree counters, then fused CSR build + weight fold ----
    hipMemsetAsync(cnt, 0, (size_t)n * 4, stream);
    build_graph_fold<<<EB + 129, 256, 0, stream>>>(
        src, dst, cnt, csr_pad, E, EB, embW, embb, gcnW, W01, b01,
        hsA + (size_t)n * 128, hsB + (size_t)n * 128);

    // ---- layer 0 GEMM (folded embedding) -> hsA ----
    gemm128<<<n / 128, 256, 0, stream>>>(x, W01, b01, cnt, hsA, n);

    // ---- fused agg0+gemm1 (hsA->hsB), agg1+gemm2 (hsB->hsA) ----
    agg_gemm<<<n / 128, 1024, 0, stream>>>(hsA, csr_pad, cnt, gcnb,
                                           gcnW + (size_t)1 * 128 * 128, hsB, n);
    agg_gemm<<<n / 128, 1024, 0, stream>>>(hsB, csr_pad, cnt, gcnb + 128,
                                           gcnW + (size_t)2 * 128 * 128, hsA, n);

    // ---- last aggregate (h + fused pooling scores) ----
    aggregate<<<n / 8, 256, 0, stream>>>(hsA, csr_pad, cnt, gcnb + 256, h,
                                         poolp, scores, n);

    // ---- fused topk pool + MLP ----
    topk_mlp<<<G, 512, 0, stream>>>(scores, h, fc1W, fc1b, fc2W, fc2b,
                                    fc3W, fc3b, out);
}

// Round 15
// 353.176 us; speedup vs baseline: 1.5319x; 1.0907x over previous
//
#include <hip/hip_runtime.h>
#include <hip/hip_bf16.h>
#include <math.h>

// N = 65536 nodes, E = 524288 edges, HID = 128, 128 graphs x 512 nodes
// fp32 throughout: absmax threshold ~9.8e-8 forbids bf16 MFMA.
// ROUND 15: REVERT to r9 (353.3us, session best). The waves/gather-depth
// axis is exhausted: r12 (cap: VGPR stayed 64, flat), r13 (force: spill,
// 160us), r14 (spill-free restructure: serialized batches, 83us). The
// fused agg_gemm floor is 62us = gather latency at compiler-chosen batch
// depth; gemm 44us VALU-bound; aggregate 45us at 48% HBM (random 512B
// gathers); boundaries ~60-70us (persistent/fusion alternatives measured
// worse in r1-r3, r7). This config is the measured Pareto optimum.

#define SLOTS 48

static __device__ __forceinline__ float4 f4add(float4 a, float4 b) {
    return make_float4(a.x + b.x, a.y + b.y, a.z + b.z, a.w + b.w);
}
static __device__ __forceinline__ float4 f4fma(float s, float4 a, float4 acc) {
    return make_float4(fmaf(s, a.x, acc.x), fmaf(s, a.y, acc.y),
                       fmaf(s, a.z, acc.z), fmaf(s, a.w, acc.w));
}

// ============ Fused: edge count+scatter (blocks 0..EB-1)  +  weight fold ====
__global__ __launch_bounds__(256) void build_graph_fold(
    const int* __restrict__ src, const int* __restrict__ dst,
    int* __restrict__ cnt, int* __restrict__ csr_pad, int E, int EB,
    const float* __restrict__ embW, const float* __restrict__ embb,
    const float* __restrict__ W0, float* __restrict__ W01,
    float* __restrict__ b01, float* __restrict__ zrowA,
    float* __restrict__ zrowB)
{
    const int b = blockIdx.x;
    if (b < EB) {
        int e = b * 256 + threadIdx.x;
        if (e < E) {
            int d = dst[e];
            int r = atomicAdd(&cnt[d], 1);
            if (r < SLOTS) csr_pad[d * SLOTS + r] = src[e];
        }
        return;
    }
    // ---- weight fold ----
    __shared__ float rs[128];
    __shared__ float part[256];
    const int r = b - EB;           // 0..128; r==128 -> bias row
    const int t = threadIdx.x;
    if (r == 0 && t < 128) { zrowA[t] = 0.f; zrowB[t] = 0.f; }
    const int c = t & 127, q = t >> 7;  // q in {0,1}
    if (t < 128) rs[t] = (r < 128) ? embW[r * 128 + t] : embb[t];
    __syncthreads();
    float s = 0.f;
    const int k0 = q * 64;
#pragma unroll 8
    for (int k = k0; k < k0 + 64; k++) s = fmaf(rs[k], W0[k * 128 + c], s);
    part[t] = s;
    __syncthreads();
    if (q == 0) {
        float v = part[c] + part[c + 128];
        if (r < 128) W01[r * 128 + c] = v;
        else         b01[c] = v;
    }
}

// ============================ GEMM: [n,128] @ [128,128] =====================
// Proven structure (44us): BM=128, 256 thr, 8x8 microtile, single-buffered
// LDS, register prefetch. ASTRIDE=129 (==1 mod 32). WSTRIDE=140 + col
// swizzle c->c+4*(c>>5). Epilogue: out = (acc + bias) * rsqrt(deg[row]+1).
#define ASTRIDE 129
#define WSTRIDE 140
__global__ __launch_bounds__(256) void gemm128(
    const float* __restrict__ A, const float* __restrict__ W,
    const float* __restrict__ bias, const int* __restrict__ rowdeg,
    float* __restrict__ out, int n)
{
    __shared__ float As[32 * ASTRIDE];  // [k][m] transposed
    __shared__ float Ws[32 * WSTRIDE];  // [k][c'] swizzled
    const int tid  = threadIdx.x;
    const int rb   = blockIdx.x * 128;
    const int tc   = tid & 15;
    const int tr   = tid >> 4;
    const int colg = tc * 8;
    const int cswz = colg + ((colg >> 5) << 2);
    const int rowg = tr * 8;

    const int a_kq = tid & 7;
    const int a_m  = tid >> 3;
    const int w_c  = (tid & 31) * 4;
    const int w_cs = w_c + ((w_c >> 5) << 2);
    const int w_k  = tid >> 5;

    float acc[8][8];
#pragma unroll
    for (int i = 0; i < 8; i++)
#pragma unroll
        for (int j = 0; j < 8; j++) acc[i][j] = 0.f;

    float4 areg[4], wreg[4];
#pragma unroll
    for (int t = 0; t < 4; t++)
        areg[t] = *(const float4*)&A[(size_t)(rb + t * 32 + a_m) * 128 + a_kq * 4];
#pragma unroll
    for (int t = 0; t < 4; t++)
        wreg[t] = *(const float4*)&W[(size_t)(t * 8 + w_k) * 128 + w_c];

#pragma unroll 1
    for (int k0 = 0; k0 < 128; k0 += 32) {
#pragma unroll
        for (int t = 0; t < 4; t++) {
            const int m = t * 32 + a_m;
            const float4 av = areg[t];
            As[(a_kq * 4 + 0) * ASTRIDE + m] = av.x;
            As[(a_kq * 4 + 1) * ASTRIDE + m] = av.y;
            As[(a_kq * 4 + 2) * ASTRIDE + m] = av.z;
            As[(a_kq * 4 + 3) * ASTRIDE + m] = av.w;
        }
#pragma unroll
        for (int t = 0; t < 4; t++)
            *(float4*)&Ws[(t * 8 + w_k) * WSTRIDE + w_cs] = wreg[t];
        __syncthreads();
        if (k0 < 96) {
#pragma unroll
            for (int t = 0; t < 4; t++)
                areg[t] = *(const float4*)&A[(size_t)(rb + t * 32 + a_m) * 128 + k0 + 32 + a_kq * 4];
#pragma unroll
            for (int t = 0; t < 4; t++)
                wreg[t] = *(const float4*)&W[(size_t)(k0 + 32 + t * 8 + w_k) * 128 + w_c];
        }
#pragma unroll 8
        for (int kk = 0; kk < 32; kk++) {
            float4 a0 = *(const float4*)&As[kk * ASTRIDE + rowg];
            float4 a1 = *(const float4*)&As[kk * ASTRIDE + rowg + 4];
            float4 b0 = *(const float4*)&Ws[kk * WSTRIDE + cswz];
            float4 b1 = *(const float4*)&Ws[kk * WSTRIDE + cswz + 4];
            float av[8] = {a0.x, a0.y, a0.z, a0.w, a1.x, a1.y, a1.z, a1.w};
            float bv[8] = {b0.x, b0.y, b0.z, b0.w, b1.x, b1.y, b1.z, b1.w};
#pragma unroll
            for (int i = 0; i < 8; i++)
#pragma unroll
                for (int j = 0; j < 8; j++) acc[i][j] = fmaf(av[i], bv[j], acc[i][j]);
        }
        __syncthreads();
    }

    float4 bb0 = make_float4(0.f, 0.f, 0.f, 0.f), bb1 = bb0;
    if (bias) {
        bb0 = *(const float4*)&bias[colg];
        bb1 = *(const float4*)&bias[colg + 4];
    }
#pragma unroll
    for (int i = 0; i < 8; i++) {
        const int row  = rb + rowg + i;
        const float sc = rowdeg ? rsqrtf((float)(rowdeg[row] + 1)) : 1.f;
        float4 o0, o1;
        o0.x = (acc[i][0] + bb0.x) * sc;  o0.y = (acc[i][1] + bb0.y) * sc;
        o0.z = (acc[i][2] + bb0.z) * sc;  o0.w = (acc[i][3] + bb0.w) * sc;
        o1.x = (acc[i][4] + bb1.x) * sc;  o1.y = (acc[i][5] + bb1.y) * sc;
        o1.z = (acc[i][6] + bb1.z) * sc;  o1.w = (acc[i][7] + bb1.w) * sc;
        *(float4*)&out[(size_t)row * 128 + colg]     = o0;
        *(float4*)&out[(size_t)row * 128 + colg + 4] = o1;
    }
}

// ============ FUSED aggregate_l + gemm_{l+1}, BM=128, 512 threads ===========
// r9 proven kernel (62us): lock-step 2-barrier panels, single-buffered LDS,
// acc[4][8], natural register allocation (VGPR 64, 16 waves/CU).
__global__ __launch_bounds__(512) void agg_gemm(
    const float* __restrict__ hs_in, const int* __restrict__ csr_pad,
    const int* __restrict__ cnt, const float* __restrict__ aggb,
    const float* __restrict__ W, float* __restrict__ hs_out, int n)
{
    __shared__ int   s_idx[128 * 17];   // clamped CSR, stride 17 (bank-free)
    __shared__ float s_dinv[128];
    __shared__ int   s_deg[128];
    __shared__ float As[32 * ASTRIDE];
    __shared__ float Ws[32 * WSTRIDE];

    const int tid = threadIdx.x;
    const int rb  = blockIdx.x * 128;
    const float4* __restrict__ hv = (const float4*)hs_in;

    if (tid < 128) {
        int d = cnt[rb + tid];
        s_deg[tid]  = d;
        s_dinv[tid] = rsqrtf((float)(d + 1));
    }
    {   // load + clamp CSR: thread t -> node t>>2, slots (t&3)*4 .. +3
        const int m    = tid >> 2;
        const int q4   = (tid & 3) * 4;
        const int node = rb + m;
        const int4 c4 = *(const int4*)&csr_pad[node * SLOTS + q4];
        const int  d  = cnt[node];
        int* row = &s_idx[m * 17 + q4];
        row[0] = (q4 + 0 < d) ? c4.x : n;
        row[1] = (q4 + 1 < d) ? c4.y : n;
        row[2] = (q4 + 2 < d) ? c4.z : n;
        row[3] = (q4 + 3 < d) ? c4.w : n;
    }
    __syncthreads();

    // gemm thread mapping: 128x128 tile, acc[4][8], 512 threads
    const int tc   = tid & 15;
    const int tr   = tid >> 4;          // 0..31
    const int colg = tc * 8;
    const int cswz = colg + ((colg >> 5) << 2);
    const int rowg = tr * 4;            // 4 rows per thread
    const int w_c  = (tid & 31) * 4;
    const int w_cs = w_c + ((w_c >> 5) << 2);
    const int w_k  = tid >> 5;          // 0..15 (2 k-rows per thread)
    // agg thread mapping: 8 lanes/node (float4 each), 64 nodes/pass
    const int ln = tid & 7;
    const int nd = tid >> 3;            // 0..63

    float acc[4][8];
#pragma unroll
    for (int i = 0; i < 4; i++)
#pragma unroll
        for (int j = 0; j < 8; j++) acc[i][j] = 0.f;

#pragma unroll 1
    for (int p = 0; p < 4; p++) {
        // issue W-panel loads early (land under the agg gathers)
        float4 wreg[2];
#pragma unroll
        for (int t = 0; t < 2; t++)
            wreg[t] = *(const float4*)&W[(size_t)(p * 32 + t * 16 + w_k) * 128 + w_c];

        // ---- aggregate this 32-feature panel: 2 passes x 64 nodes ----
        const int fo = p * 8 + ln;          // float4 offset within a row
        const float4 bb = *(const float4*)&aggb[p * 32 + ln * 4];
#pragma unroll 1
        for (int ps = 0; ps < 2; ps++) {
            const int m    = ps * 64 + nd;
            const int node = rb + m;
            const int* rowI = &s_idx[m * 17];
            float4 self = hv[(size_t)node * 32 + fo];
            float4 r[16];
#pragma unroll
            for (int j = 0; j < 16; j++)
                r[j] = hv[(size_t)rowI[j] * 32 + fo];
            asm volatile("" ::: "memory");
            float4 a0 = self;
            float4 a1 = make_float4(0.f, 0.f, 0.f, 0.f);
            float4 a2 = a1, a3 = a1;
#pragma unroll
            for (int j = 0; j < 16; j += 4) {
                a0 = f4add(a0, r[j + 0]);
                a1 = f4add(a1, r[j + 1]);
                a2 = f4add(a2, r[j + 2]);
                a3 = f4add(a3, r[j + 3]);
            }
            const int d    = s_deg[m];
            const int dcap = d < SLOTS ? d : SLOTS;
            for (int j = 16; j < dcap; j++)  // rare tail (deg > 16)
                a1 = f4add(a1, hv[(size_t)csr_pad[node * SLOTS + j] * 32 + fo]);
            float4 s = f4add(f4add(a0, a1), f4add(a2, a3));
            const float dv = s_dinv[m];
            float4 o;
            o.x = fmaxf(fmaf(s.x, dv, bb.x), 0.f);
            o.y = fmaxf(fmaf(s.y, dv, bb.y), 0.f);
            o.z = fmaxf(fmaf(s.z, dv, bb.z), 0.f);
            o.w = fmaxf(fmaf(s.w, dv, bb.w), 0.f);
            const int kb = ln * 4;
            As[(kb + 0) * ASTRIDE + m] = o.x;
            As[(kb + 1) * ASTRIDE + m] = o.y;
            As[(kb + 2) * ASTRIDE + m] = o.z;
            As[(kb + 3) * ASTRIDE + m] = o.w;
        }
#pragma unroll
        for (int t = 0; t < 2; t++)
            *(float4*)&Ws[(t * 16 + w_k) * WSTRIDE + w_cs] = wreg[t];
        __syncthreads();

        // ---- gemm partial-K: acc[4][8], A read = one float4 of 4 rows ----
#pragma unroll 8
        for (int kk = 0; kk < 32; kk++) {
            float4 a0 = *(const float4*)&As[kk * ASTRIDE + rowg];
            float4 b0 = *(const float4*)&Ws[kk * WSTRIDE + cswz];
            float4 b1 = *(const float4*)&Ws[kk * WSTRIDE + cswz + 4];
            float av[4] = {a0.x, a0.y, a0.z, a0.w};
            float bv[8] = {b0.x, b0.y, b0.z, b0.w, b1.x, b1.y, b1.z, b1.w};
#pragma unroll
            for (int i = 0; i < 4; i++)
#pragma unroll
                for (int j = 0; j < 8; j++) acc[i][j] = fmaf(av[i], bv[j], acc[i][j]);
        }
        __syncthreads();
    }

    // epilogue: source-side dinv scaling for the next layer, no bias
#pragma unroll
    for (int i = 0; i < 4; i++) {
        const int row  = rb + rowg + i;
        const float sc = s_dinv[rowg + i];
        float4 o0, o1;
        o0.x = acc[i][0] * sc;  o0.y = acc[i][1] * sc;
        o0.z = acc[i][2] * sc;  o0.w = acc[i][3] * sc;
        o1.x = acc[i][4] * sc;  o1.y = acc[i][5] * sc;
        o1.z = acc[i][6] * sc;  o1.w = acc[i][7] * sc;
        *(float4*)&hs_out[(size_t)row * 128 + colg]     = o0;
        *(float4*)&hs_out[(size_t)row * 128 + colg + 4] = o1;
    }
}

// ============================ Aggregation (last layer) ======================
// Proven r4 kernel, byte-identical: zero-row gather, int4 CSR loads,
// fused pooling score.
__global__ __launch_bounds__(256) void aggregate(
    const float* __restrict__ hs, const int* __restrict__ csr_pad,
    const int* __restrict__ cnt, const float* __restrict__ bias,
    float* __restrict__ hout,
    const float* __restrict__ pool_p, float* __restrict__ scores, int n)
{
    const int grp  = threadIdx.x >> 5;
    const int lane = threadIdx.x & 31;
    const int node = blockIdx.x * 8 + grp;
    const float4* __restrict__ hv = (const float4*)hs;

    const int deg = cnt[node];
    const int e0  = node * SLOTS;

    int4 c4[4];
#pragma unroll
    for (int q = 0; q < 4; q++)
        c4[q] = *(const int4*)&csr_pad[e0 + q * 4];
    int ix[16] = {c4[0].x, c4[0].y, c4[0].z, c4[0].w,
                  c4[1].x, c4[1].y, c4[1].z, c4[1].w,
                  c4[2].x, c4[2].y, c4[2].z, c4[2].w,
                  c4[3].x, c4[3].y, c4[3].z, c4[3].w};
#pragma unroll
    for (int j = 0; j < 16; j++)
        ix[j] = (j < deg) ? ix[j] : n;       // poison -> zero row

    float4 self = hv[(size_t)node * 32 + lane];
    float4 r[16];
#pragma unroll
    for (int j = 0; j < 16; j++)
        r[j] = hv[(size_t)ix[j] * 32 + lane];
    asm volatile("" ::: "memory");  // keep the 16 loads in flight before use

    float4 a0 = self;
    float4 a1 = make_float4(0.f, 0.f, 0.f, 0.f);
    float4 a2 = a1, a3 = a1;
#pragma unroll
    for (int j = 0; j < 16; j += 4) {
        a0 = f4add(a0, r[j + 0]);
        a1 = f4add(a1, r[j + 1]);
        a2 = f4add(a2, r[j + 2]);
        a3 = f4add(a3, r[j + 3]);
    }
    const int dcap = deg < SLOTS ? deg : SLOTS;
    for (int j = 16; j < dcap; j++) {  // rare tail (deg > 16)
        a1 = f4add(a1, hv[(size_t)csr_pad[e0 + j] * 32 + lane]);
    }

    float4 s = f4add(f4add(a0, a1), f4add(a2, a3));
    const float dv = rsqrtf((float)(deg + 1));
    const float4 bb = ((const float4*)bias)[lane];
    float4 o;
    o.x = fmaxf(fmaf(s.x, dv, bb.x), 0.f);
    o.y = fmaxf(fmaf(s.y, dv, bb.y), 0.f);
    o.z = fmaxf(fmaf(s.z, dv, bb.z), 0.f);
    o.w = fmaxf(fmaf(s.w, dv, bb.w), 0.f);
    ((float4*)hout)[(size_t)node * 32 + lane] = o;

    if (scores) {  // wave-uniform branch (fused pooling score)
        float4 pv = ((const float4*)pool_p)[lane];
        float d  = o.x * pv.x + o.y * pv.y + o.z * pv.z + o.w * pv.w;
        float nn = pv.x * pv.x + pv.y * pv.y + pv.z * pv.z + pv.w * pv.w;
#pragma unroll
        for (int off = 16; off > 0; off >>= 1) {
            d  += __shfl_xor(d, off);
            nn += __shfl_xor(nn, off);
        }
        if (lane == 0) scores[node] = d * rsqrtf(nn);
    }
}

// ==================== TopK pool (k=256 of 512) + MLP head ===================
__global__ __launch_bounds__(512) void topk_mlp(
    const float* __restrict__ scores, const float* __restrict__ h,
    const float* __restrict__ fc1W, const float* __restrict__ fc1b,
    const float* __restrict__ fc2W, const float* __restrict__ fc2b,
    const float* __restrict__ fc3W, const float* __restrict__ fc3b,
    float* __restrict__ out)
{
    __shared__ float s[512];
    __shared__ int   sel[256];
    __shared__ float w[256];
    __shared__ float4 red[512];
    __shared__ float pld[128];
    __shared__ float z1[128];
    __shared__ float z2[64];
    const int g = blockIdx.x;
    const int i = threadIdx.x;
    s[i] = scores[g * 512 + i];
    __syncthreads();
    float si = s[i];
    int rank = 0;
    for (int j = 0; j < 512; j++) {
        float sj = s[j];
        rank += (sj > si) || (sj == si && j < i);
    }
    if (rank < 256) {
        sel[rank] = i;
        w[rank]   = tanhf(si) * (1.f / 256.f);
    }
    __syncthreads();
    const int c   = (i & 31) * 4;
    const int grp = i >> 5;
    float4 acc = make_float4(0.f, 0.f, 0.f, 0.f);
    for (int t = grp; t < 256; t += 16) {
        float wt  = w[t];
        int   idx = sel[t];
        float4 r = *(const float4*)&h[((size_t)g * 512 + idx) * 128 + c];
        acc = f4fma(wt, r, acc);
    }
    red[i] = acc;
    __syncthreads();
    if (i < 256) red[i] = f4add(red[i], red[i + 256]);
    __syncthreads();
    if (i < 128) red[i] = f4add(red[i], red[i + 128]);
    __syncthreads();
    if (i < 64) red[i] = f4add(red[i], red[i + 64]);
    __syncthreads();
    if (i < 32) {
        float4 v = f4add(red[i], red[i + 32]);
        *(float4*)&pld[i * 4] = v;
    }
    __syncthreads();
    if (i < 128) {
        float a = fc1b[i];
        for (int k = 0; k < 128; k++) a += pld[k] * fc1W[k * 128 + i];
        z1[i] = fmaxf(a, 0.f);
    }
    __syncthreads();
    if (i < 64) {
        float b = fc2b[i];
        for (int k = 0; k < 128; k++) b += z1[k] * fc2W[k * 64 + i];
        z2[i] = fmaxf(b, 0.f);
    }
    __syncthreads();
    if (i < 10) {
        float o = fc3b[i];
        for (int k = 0; k < 64; k++) o += z2[k] * fc3W[k * 10 + i];
        out[g * 10 + i] = o;
    }
}

// ============================ Launcher ======================================
extern "C" void kernel_launch(void* const* d_in, const int* in_sizes, int n_in,
                              void* d_out, int out_size, void* d_ws, size_t ws_size,
                              hipStream_t stream)
{
    const float* x     = (const float*)d_in[0];
    const int*   eidx  = (const int*)d_in[1];
    const float* embW  = (const float*)d_in[3];
    const float* embb  = (const float*)d_in[4];
    const float* gcnW  = (const float*)d_in[5];
    const float* gcnb  = (const float*)d_in[6];
    const float* poolp = (const float*)d_in[7];
    const float* fc1W  = (const float*)d_in[8];
    const float* fc1b  = (const float*)d_in[9];
    const float* fc2W  = (const float*)d_in[10];
    const float* fc2b  = (const float*)d_in[11];
    const float* fc3W  = (const float*)d_in[12];
    const float* fc3b  = (const float*)d_in[13];
    float* out = (float*)d_out;

    const int n = in_sizes[0] / 128;   // 65536
    const int E = in_sizes[1] / 2;     // 524288
    const int G = n / 512;             // 128

    const int* src = eidx;
    const int* dst = eidx + E;

    char* ws = (char*)d_ws;
    size_t off = 0;
    auto carve = [&](size_t bytes) {
        void* p = ws + off;
        off += (bytes + 255) & ~(size_t)255;
        return p;
    };
    float* h       = (float*)carve((size_t)n * 128 * 4);
    float* hsA     = (float*)carve((size_t)(n + 1) * 128 * 4);  // +zero row
    float* hsB     = (float*)carve((size_t)(n + 1) * 128 * 4);  // +zero row
    int*   cnt     = (int*)carve((size_t)n * 4);
    int*   csr_pad = (int*)carve((size_t)n * SLOTS * 4);
    float* scores  = (float*)carve((size_t)n * 4);
    float* W01     = (float*)carve(128 * 128 * 4);
    float* b01     = (float*)carve(128 * 4);
    (void)ws_size;

    const int EB = E / 256;            // 2048 edge blocks

    // ---- zero degree counters, then fused CSR build + weight fold ----
    hipMemsetAsync(cnt, 0, (size_t)n * 4, stream);
    build_graph_fold<<<EB + 129, 256, 0, stream>>>(
        src, dst, cnt, csr_pad, E, EB, embW, embb, gcnW, W01, b01,
        hsA + (size_t)n * 128, hsB + (size_t)n * 128);

    // ---- layer 0 GEMM (folded embedding) -> hsA ----
    gemm128<<<n / 128, 256, 0, stream>>>(x, W01, b01, cnt, hsA, n);

    // ---- fused agg0+gemm1 (hsA->hsB), agg1+gemm2 (hsB->hsA) ----
    agg_gemm<<<n / 128, 512, 0, stream>>>(hsA, csr_pad, cnt, gcnb,
                                          gcnW + (size_t)1 * 128 * 128, hsB, n);
    agg_gemm<<<n / 128, 512, 0, stream>>>(hsB, csr_pad, cnt, gcnb + 128,
                                          gcnW + (size_t)2 * 128 * 128, hsA, n);

    // ---- last aggregate (h + fused pooling scores) ----
    aggregate<<<n / 8, 256, 0, stream>>>(hsA, csr_pad, cnt, gcnb + 256, h,
                                         poolp, scores, n);

    // ---- fused topk pool + MLP ----
    topk_mlp<<<G, 512, 0, stream>>>(scores, h, fc1W, fc1b, fc2W, fc2b,
                                    fc3W, fc3b, out);
}